// Round 4
// baseline (392.789 us; speedup 1.0000x reference)
//
#include <hip/hip_runtime.h>
#include <math.h>

#define BB 8
#define CC 256
#define HH 128
#define WW 128
#define HWP 16384          // 128*128
#define MH 512
#define MW 512
#define NPIX (BB*HWP)      // 131072
#define IQ 4096            // HWP/4 quads per image

#define TW 64
#define TH 4
#define IW 70
#define IH 10
#define PITCH 72

typedef float f32x4_t __attribute__((ext_vector_type(4)));

// Poison-proof flag tags: a pair (v, ~v) can never be produced by a constant
// fill pattern. Distinct multipliers for the two flag families.
__device__ __forceinline__ unsigned tag1(int i) { return (unsigned)(i + 1) * 2654435761u; }
__device__ __forceinline__ unsigned tag2(int i) { return (unsigned)(i + 1) * 1597334677u; }

__device__ __forceinline__ void sig(unsigned* f, int idx, unsigned v) {
    // device-scope atomics land at the coherent point (cross-XCD safe)
    atomicExch(&f[2 * idx], v);
    atomicExch(&f[2 * idx + 1], ~v);
}

// Wait until pairs [base, base+count) are all signalled. Atomic-RMW polls read
// the coherent point (per-XCD L2s are not cross-coherent; plain loads could
// hit stale lines cached by a previous iteration's poll). Acquire fence before
// returning so subsequent plain data loads miss stale L1/L2.
template <bool K2>
__device__ __forceinline__ void wait_pairs(unsigned* f, int base, int count) {
    while (true) {
        bool ok = true;
        for (int i = threadIdx.x; i < count; i += 256) {
            int idx = base + i;
            unsigned v = K2 ? tag2(idx) : tag1(idx);
            unsigned a = atomicOr(&f[2 * idx], 0u);
            unsigned b = atomicOr(&f[2 * idx + 1], 0u);
            if (a != v || b != ~v) ok = false;
        }
        if (__syncthreads_and(ok)) break;
        __builtin_amdgcn_s_sleep(8);
    }
    __builtin_amdgcn_fence(__ATOMIC_ACQUIRE, "agent");
}

// ---------------------------------------------------------------------------
// Single fused kernel: 1024 blocks x 256 threads = exactly 4 blocks/CU, all
// co-resident (launch_bounds caps VGPR at 128, LDS 9.3KB) -> flag spin-waits
// are deadlock-free by construction, no dispatch-order assumptions.
//   Phase 1: even blocks mask-resize; odd blocks x channel partial sum/max.
//            (identical math to the verified 3-kernel pipeline)
//   Phase 2: even block e waits on image-A phase-1 flags (A = e>>7), then
//            computes k2 conv tile T = e>>1, signals tile flag.
//   Phase 3: block handles planes bid and bid+1024, each gated on that
//            image's 64 tile flags. x NT-loaded, out NT-stored.
// ---------------------------------------------------------------------------
__global__ __launch_bounds__(256, 4) void k_all(
    const float* __restrict__ masks, const float* __restrict__ x,
    const float* __restrict__ cw, const float* __restrict__ gamma,
    const float* __restrict__ beta, float* __restrict__ out,
    float* __restrict__ m_out, float* __restrict__ cs,
    float* __restrict__ cm, float* __restrict__ wprod,
    unsigned* __restrict__ f1, unsigned* __restrict__ f2)
{
    __shared__ float w[147];
    __shared__ float pa[IH * PITCH], px[IH * PITCH], pm[IH * PITCH];
    __shared__ float ls[4], lss[4], smu, srs;

    const int bid = blockIdx.x, tid = threadIdx.x;

    // ---------------- Phase 1 ----------------
    if ((bid & 1) == 0) {
        // ---- mask resize path ----
        int t = (bid >> 1) * 256 + tid;            // 0..NPIX-1
        int j = t & 127, i = (t >> 7) & 127, b = t >> 14;
        const float Wt[8] = {1.f, 3.f, 5.f, 7.f, 7.f, 5.f, 3.f, 1.f};
        const float* mb = masks + (size_t)b * (MH * MW);
        int r0 = 4 * i - 2, c0 = 4 * j - 2;
        float cwgt[8];
        int ccl[8];
        float sh = 0.f;
        #pragma unroll
        for (int q = 0; q < 8; q++) {
            int c = c0 + q;
            bool v = (unsigned)c < (unsigned)MW;
            cwgt[q] = v ? Wt[q] : 0.f;
            sh += cwgt[q];
            ccl[q] = min(max(c, 0), MW - 1);
        }
        float acc = 0.f, sv = 0.f;
        #pragma unroll
        for (int p = 0; p < 8; p++) {
            int r = r0 + p;
            bool v = (unsigned)r < (unsigned)MH;
            float wp = v ? Wt[p] : 0.f;
            sv += wp;
            const float* row = mb + (size_t)min(max(r, 0), MH - 1) * MW;
            float ra = 0.f;
            #pragma unroll
            for (int q = 0; q < 8; q++) ra += cwgt[q] * row[ccl[q]];
            acc += wp * ra;
        }
        m_out[t] = acc / (sv * sh);
    } else {
        // ---- channel partial-reduce path ----
        int id = bid >> 1;               // 0..511 = b(3) | g(2) | chunk(4)
        int chunk = id & 15;
        int g = (id >> 4) & 3;
        int b = id >> 6;
        int qi = chunk * 256 + tid;      // quad index within image
        const float4* xb = (const float4*)x + ((size_t)(b * CC + g * 64)) * IQ + qi;
        float4 s = {0.f, 0.f, 0.f, 0.f};
        float4 mx = {-INFINITY, -INFINITY, -INFINITY, -INFINITY};
        #pragma unroll 8
        for (int c = 0; c < 64; c++) {
            float4 v = xb[(size_t)c * IQ];
            s.x += v.x; s.y += v.y; s.z += v.z; s.w += v.w;
            mx.x = fmaxf(mx.x, v.x); mx.y = fmaxf(mx.y, v.y);
            mx.z = fmaxf(mx.z, v.z); mx.w = fmaxf(mx.w, v.w);
        }
        size_t o = (size_t)g * (NPIX / 4) + (size_t)b * IQ + qi;
        ((float4*)cs)[o] = s;
        ((float4*)cm)[o] = mx;
    }
    __syncthreads();   // drains all threads' stores (compiler emits vmcnt(0))
    if (tid == 0) {
        __builtin_amdgcn_fence(__ATOMIC_RELEASE, "agent");  // L2 writeback
        sig(f1, bid, tag1(bid));
    }

    // ---------------- Phase 2 (even blocks only) ----------------
    if ((bid & 1) == 0) {
        int T = bid >> 1;                // tile 0..511
        int A = T >> 6;                  // image
        // image A's phase-1 producers are exactly blocks [A*128, A*128+128)
        wait_pairs<false>(f1, A * 128, 128);
        if (tid < 147) w[tid] = cw[tid];
        int bx = T & 1, by = (T >> 1) & 31, b = T >> 6;
        int ox = bx * TW - 3, oy = by * TH - 3;
        for (int idx = tid; idx < IW * IH; idx += 256) {
            int r = idx / IW, c = idx - r * IW;
            int gi = oy + r, gj = ox + c;
            float av = 0.f, mxv = 0.f, mv = 0.f;
            if ((unsigned)gi < (unsigned)HH && (unsigned)gj < (unsigned)WW) {
                int p = b * HWP + gi * WW + gj;
                mv = m_out[p];
                float sfull = cs[p] + cs[p + NPIX] + cs[p + 2 * NPIX] + cs[p + 3 * NPIX];
                float mmx = fmaxf(fmaxf(cm[p], cm[p + NPIX]),
                                  fmaxf(cm[p + 2 * NPIX], cm[p + 3 * NPIX]));
                av = mv * sfull * (1.f / 256.f);
                mxv = mv * mmx;
            }
            pa[r * PITCH + c] = av;
            px[r * PITCH + c] = mxv;
            pm[r * PITCH + c] = mv;
        }
        __syncthreads();
        int col = tid & 63, r = tid >> 6;
        float acc = 0.f;
        #pragma unroll
        for (int di = 0; di < 7; di++) {
            #pragma unroll
            for (int dj = 0; dj < 7; dj++) {
                int li = (r + di) * PITCH + col + dj;
                acc += w[di * 7 + dj] * pa[li];
                acc += w[49 + di * 7 + dj] * px[li];
                acc += w[98 + di * 7 + dj] * pm[li];
            }
        }
        float at = 1.f / (1.f + expf(-acc));
        float res = pm[(r + 3) * PITCH + col + 3] * at;
        wprod[b * HWP + (by * TH + r) * WW + bx * TW + col] = res;
        __syncthreads();
        if (tid == 0) {
            __builtin_amdgcn_fence(__ATOMIC_RELEASE, "agent");
            sig(f2, T, tag2(T));
        }
    }

    // ---------------- Phase 3: two planes per block ----------------
    #pragma unroll 1
    for (int half = 0; half < 2; half++) {
        int bc = bid + half * 1024;      // plane index b*256+c
        int b = bc >> 8, c = bc & 255;
        // image b's conv tiles are exactly f2 pairs [b*64, b*64+64)
        wait_pairs<true>(f2, b * 64, 64);
        const f32x4_t* xp = (const f32x4_t*)(x + (size_t)bc * HWP);
        const float4* wpv = (const float4*)(wprod + (size_t)b * HWP);
        f32x4_t o[16];
        float s = 0.f, ss = 0.f;
        #pragma unroll
        for (int k = 0; k < 16; k++) {
            int idx = tid + k * 256;
            f32x4_t xv = __builtin_nontemporal_load(xp + idx);
            float4 wv = wpv[idx];
            f32x4_t ov;
            ov.x = xv.x * wv.x; ov.y = xv.y * wv.y;
            ov.z = xv.z * wv.z; ov.w = xv.w * wv.w;
            o[k] = ov;
            s += ov.x + ov.y + ov.z + ov.w;
            ss += ov.x * ov.x + ov.y * ov.y + ov.z * ov.z + ov.w * ov.w;
        }
        #pragma unroll
        for (int off = 32; off; off >>= 1) {
            s += __shfl_down(s, off, 64);
            ss += __shfl_down(ss, off, 64);
        }
        int wave = tid >> 6, lane = tid & 63;
        if (lane == 0) { ls[wave] = s; lss[wave] = ss; }
        __syncthreads();
        if (tid == 0) {
            float S = ls[0] + ls[1] + ls[2] + ls[3];
            float SS = lss[0] + lss[1] + lss[2] + lss[3];
            float mu = S * (1.f / HWP);
            float var = fmaxf(SS * (1.f / HWP) - mu * mu, 0.f);
            smu = mu;
            srs = rsqrtf(var + 1e-5f);
        }
        __syncthreads();
        float mu = smu;
        float g5 = 5.f * srs * gamma[c];
        float b5 = 5.f * beta[c];
        f32x4_t* op = (f32x4_t*)(out + (size_t)bc * HWP);
        #pragma unroll
        for (int k = 0; k < 16; k++) {
            int idx = tid + k * 256;
            f32x4_t ov = o[k];
            f32x4_t r;
            r.x = fmaxf(fmaf(ov.x - mu, g5, b5), 0.f);
            r.y = fmaxf(fmaf(ov.y - mu, g5, b5), 0.f);
            r.z = fmaxf(fmaf(ov.z - mu, g5, b5), 0.f);
            r.w = fmaxf(fmaf(ov.w - mu, g5, b5), 0.f);
            __builtin_nontemporal_store(r, op + idx);
        }
        __syncthreads();   // protect ls/lss/smu/srs reuse across halves
    }
}

extern "C" void kernel_launch(void* const* d_in, const int* in_sizes, int n_in,
                              void* d_out, int out_size, void* d_ws, size_t ws_size,
                              hipStream_t stream) {
    const float* x      = (const float*)d_in[0];
    const float* masks  = (const float*)d_in[1];
    const float* conv_w = (const float*)d_in[2];
    const float* gamma  = (const float*)d_in[3];
    const float* beta   = (const float*)d_in[4];
    float* out = (float*)d_out;

    float* ws = (float*)d_ws;
    float* m_arr = ws;                       // [NPIX]
    float* cs    = ws + (size_t)NPIX;        // [4*NPIX]
    float* cm    = ws + (size_t)5 * NPIX;    // [4*NPIX]
    float* wprod = ws + (size_t)9 * NPIX;    // [NPIX]
    unsigned* f1 = (unsigned*)(ws + (size_t)10 * NPIX);   // 1024 pairs
    unsigned* f2 = f1 + 2048;                             // 512 pairs

    k_all<<<1024, 256, 0, stream>>>(masks, x, conv_w, gamma, beta, out,
                                    m_arr, cs, cm, wprod, f1, f2);
}